// Round 6
// baseline (252.371 us; speedup 1.0000x reference)
//
#include <hip/hip_runtime.h>

#define S_SEQ 256
#define N_RES 512
#define CCH   32

typedef __attribute__((ext_vector_type(8))) short bf16x8;
typedef __attribute__((ext_vector_type(4))) float f32x4;
typedef __attribute__((ext_vector_type(2))) unsigned int u32x2;

__device__ __forceinline__ unsigned short f2bf(float x) {
    unsigned int u = __float_as_uint(x);
    return (unsigned short)((u + 0x7FFFu + ((u >> 16) & 1u)) >> 16);
}

#define GLOAD_LDS16(gp, lp) __builtin_amdgcn_global_load_lds( \
    (const __attribute__((address_space(1))) unsigned int*)(gp), \
    (__attribute__((address_space(3))) unsigned int*)(lp), 16, 0, 0)

#define BAR()    do { __builtin_amdgcn_s_barrier(); asm volatile("" ::: "memory"); } while (0)
#define WLGKM0() asm volatile("s_waitcnt lgkmcnt(0)" ::: "memory")
#define WVM(n)   asm volatile("s_waitcnt vmcnt(" #n ")" ::: "memory")

// ---------------------------------------------------------------------------
// Kernel 1: LayerNorm + dual projection + mask. Writes A/B bf16 as the exact
// LDS byte image kmain6 stages. Per 256-row tile, per KT-32 (32 seqs):
//   rows r and r+128 share a 128-B image row ir = r&127 (8 slots of 16 B):
//   byte = kt*16384 + ir*128 + ((((r>>7)<<2)|(k>>3)) ^ (ir&7))*16 + (k&7)*2
// Conflict-free: a wave's b128 frag read hits each 16B slot-column exactly
// 8 times (bank = slot*4 only, since ir*128/4 mod 32 == 0).
// ---------------------------------------------------------------------------
__global__ __launch_bounds__(256) void prep_ab(
    const float* __restrict__ m, const float* __restrict__ mask,
    const float* __restrict__ gam, const float* __restrict__ bet,
    const float* __restrict__ Wa, const float* __restrict__ ba,
    const float* __restrict__ Wb, const float* __restrict__ bb,
    char* __restrict__ Ag, char* __restrict__ Bg)
{
    __shared__ float WaL[1024], WbL[1024];
    __shared__ float gL[32], btL[32], baL[32], bbL[32];
    __shared__ unsigned short At[32 * 256];
    __shared__ unsigned short Bt[32 * 256];

    const int n = blockIdx.x;
    const int t = threadIdx.x;

    for (int i = t; i < 1024; i += 256) { WaL[i] = Wa[i]; WbL[i] = Wb[i]; }
    if (t < 32) { gL[t] = gam[t]; btL[t] = bet[t]; baL[t] = ba[t]; bbL[t] = bb[t]; }
    __syncthreads();

    const int s = t;
    float mv[32];
    const float* mrow = m + ((size_t)s * N_RES + n) * CCH;
#pragma unroll
    for (int c4 = 0; c4 < 8; c4++) {
        f32x4 v = *(const f32x4*)(mrow + c4 * 4);
        mv[c4 * 4 + 0] = v.x; mv[c4 * 4 + 1] = v.y;
        mv[c4 * 4 + 2] = v.z; mv[c4 * 4 + 3] = v.w;
    }
    float mu = 0.f;
#pragma unroll
    for (int c = 0; c < 32; c++) mu += mv[c];
    mu *= (1.f / 32.f);
    float var = 0.f;
#pragma unroll
    for (int c = 0; c < 32; c++) { float d = mv[c] - mu; var += d * d; }
    var *= (1.f / 32.f);
    float rs = rsqrtf(var + 1e-5f);
    float mh[32];
#pragma unroll
    for (int c = 0; c < 32; c++) mh[c] = (mv[c] - mu) * rs * gL[c] + btL[c];

    const float msk = mask[(size_t)s * N_RES + n];

    f32x4 av[8], bv[8];
#pragma unroll
    for (int cg = 0; cg < 8; cg++) { av[cg] = (f32x4)0.f; bv[cg] = (f32x4)0.f; }
#pragma unroll
    for (int k = 0; k < 32; k++) {
        float x = mh[k];
#pragma unroll
        for (int cg = 0; cg < 8; cg++) {
            f32x4 wa4 = *(const f32x4*)&WaL[k * 32 + cg * 4];
            f32x4 wb4 = *(const f32x4*)&WbL[k * 32 + cg * 4];
            av[cg] += x * wa4;
            bv[cg] += x * wb4;
        }
    }
#pragma unroll
    for (int cg = 0; cg < 8; cg++) {
#pragma unroll
        for (int u = 0; u < 4; u++) {
            int c = cg * 4 + u;
            At[c * 256 + s] = f2bf((av[cg][u] + baL[c]) * msk);
            Bt[c * 256 + s] = f2bf((bv[cg][u] + bbL[c]) * msk);
        }
    }
    __syncthreads();

    // flush in kmain6's dual-row 128B image (16B chunks)
    const size_t tbase = (size_t)(n >> 3) * 131072;
    const int half = (n >> 2) & 1;                 // r = (n&7)*32 + c ; half = r>>7
    const int irbase = (n & 3) * 32;               // ir = r&127
#pragma unroll
    for (int u = 0; u < 4; u++) {
        int cid = t * 4 + u;             // 1024 chunks: c (32) x 8-seq group g (32)
        int c = cid >> 5, g = cid & 31;
        int kt = g >> 2, q = g & 3;      // s = kt*32 + q*8 + j
        int slot = ((half << 2) | q) ^ (c & 7);    // ir&7 == c&7
        size_t off = tbase + (size_t)kt * 16384 + (size_t)(irbase + c) * 128 + (slot << 4);
        *(uint4*)(Ag + off) = *(const uint4*)(At + c * 256 + g * 8);
        *(uint4*)(Bg + off) = *(const uint4*)(Bt + c * 256 + g * 8);
    }
}

// ---------------------------------------------------------------------------
// Kernel 2: Wt3[e][ch][c] = bf16(Wout[(c*32+e)][ch])   (32 x 32 x 32 bf16)
// ---------------------------------------------------------------------------
__global__ __launch_bounds__(256) void kwt(const float* __restrict__ Wout,
                                           unsigned short* __restrict__ Wt3)
{
    int idx = blockIdx.x * 256 + threadIdx.x;   // 32768
    int e = idx >> 10, ch = (idx >> 5) & 31, c = idx & 31;
    Wt3[idx] = f2bf(Wout[(size_t)(c * 32 + e) * 32 + ch]);
}

// ---------------------------------------------------------------------------
// Kernel 3: inv_norm[i][j] = 1 / (sum_s mask[s,i]*mask[s,j] + 1e-3)
// ---------------------------------------------------------------------------
__global__ __launch_bounds__(256) void knorm(const float* __restrict__ mask,
                                             float* __restrict__ inv_norm)
{
    __shared__ float Mi[64][65];
    __shared__ float Mj[64][65];
    const int bi = blockIdx.x >> 3, bj = blockIdx.x & 7;
    const int t = threadIdx.x;
    const int ty = t >> 4, tx = t & 15;

    float acc[4][4];
#pragma unroll
    for (int a = 0; a < 4; a++)
#pragma unroll
        for (int b = 0; b < 4; b++) acc[a][b] = 0.f;

    for (int sc = 0; sc < 4; sc++) {
        for (int e = t; e < 4096; e += 256) {
            int sr = e >> 6, col = e & 63;
            Mi[sr][col] = mask[(size_t)(sc * 64 + sr) * N_RES + bi * 64 + col];
            Mj[sr][col] = mask[(size_t)(sc * 64 + sr) * N_RES + bj * 64 + col];
        }
        __syncthreads();
        for (int sp = 0; sp < 64; sp++) {
#pragma unroll
            for (int a = 0; a < 4; a++)
#pragma unroll
                for (int b = 0; b < 4; b++)
                    acc[a][b] += Mi[sp][ty * 4 + a] * Mj[sp][tx * 4 + b];
        }
        __syncthreads();
    }
#pragma unroll
    for (int a = 0; a < 4; a++)
#pragma unroll
        for (int b = 0; b < 4; b++) {
            int i = bi * 64 + ty * 4 + a;
            int j = bj * 64 + tx * 4 + b;
            inv_norm[(size_t)i * N_RES + j] = 1.f / (acc[a][b] + 1e-3f);
        }
}

// ---------------------------------------------------------------------------
// Kernel 6: 256x256 tile, BK=64, dbuf 2x64KB (LDS 128KB), m201-style phased
// schedule: 4 K-64 tiles x 4 phases, each phase = {ds_reads + staging issue,
// barrier, lgkmcnt(0), setprio(1) + 16 MFMA + setprio(0), barrier}. Staging
// for tile T+1 issued in T's phases 0-1, gated by one vmcnt(0) at T's phase-3
// end (loads stay in flight across 8 barriers). Epilogue: r5-verified.
// ---------------------------------------------------------------------------
__global__ __launch_bounds__(512, 2) void kmain6(
    const char* __restrict__ Ag, const char* __restrict__ Bg,
    const unsigned short* __restrict__ Wt3, const float* __restrict__ inv_norm,
    const float* __restrict__ bout, float* __restrict__ out)
{
    __shared__ __align__(16) char sm[131072];  // 2 x 64KB dbuf; epi overlays [0,66048)

    const int bid = blockIdx.x;
    const int xcd = bid & 7;
    const int xidx = bid >> 3;
    const int chunk = xidx >> 7;
    const int TI = xcd * 8 + ((xidx >> 4) & 7);
    const int TJ = chunk * 16 + (xidx & 15);

    const int t = threadIdx.x;
    const int lane = t & 63, wid = t >> 6;
    const int wr = wid >> 2, wc = wid & 3;     // wave tile 128x64
    const int rl = lane & 15, h4 = lane >> 4;

    const char* pa = Ag + (size_t)TI * 131072;
    const char* pb = Bg + (size_t)TJ * 131072;

    // lane-constant frag offsets (within a 16KB KT-32 image)
    const int aslot = ((wr << 2) | h4) ^ (rl & 7);
    const int bslot = (((wc >> 1) << 2) | h4) ^ (rl & 7);
    const int abase = rl * 128 + (aslot << 4);                        // + m*2048
    const int bbase = ((wc & 1) * 64 + rl) * 128 + (bslot << 4);      // + n*2048

    // stage chunk c (0..7) of K-64 tile T1: A chunks 0-3 (32KB), B chunks 4-7
#define SCH(T1, c) GLOAD_LDS16( \
    (((c) < 4) ? pa : pb) + (T1) * 32768 + ((c) & 3) * 8192 + t * 16, \
    sm + (((T1) & 1) * 65536) + (((c) < 4) ? 0 : 32768) + ((c) & 3) * 8192 + t * 16)

#define FRAG_A(dst, bufc, k, MB) do { \
    _Pragma("unroll") \
    for (int mm = 0; mm < 4; mm++) \
        dst[mm] = *(const bf16x8*)((bufc) + (k) * 16384 + abase + ((MB) + mm) * 2048); \
} while (0)

#define FRAG_B(dst, bufc, k) do { \
    _Pragma("unroll") \
    for (int nn = 0; nn < 4; nn++) \
        dst[nn] = *(const bf16x8*)((bufc) + 32768 + (k) * 16384 + bbase + nn * 2048); \
} while (0)

#define MFMA16(A4, B4, MB) do { \
    __builtin_amdgcn_s_setprio(1); \
    _Pragma("unroll") \
    for (int mm = 0; mm < 4; mm++) \
        _Pragma("unroll") \
        for (int nn = 0; nn < 4; nn++) \
            acc[(MB) + mm][nn] = __builtin_amdgcn_mfma_f32_16x16x32_bf16( \
                A4[mm], B4[nn], acc[(MB) + mm][nn], 0, 0, 0); \
    __builtin_amdgcn_s_setprio(0); \
} while (0)

#define KTILE(T) do { \
    const char* bufc = sm + (((T) & 1) * 65536); \
    bf16x8 a0[4], a1[4], b0[4], b1[4]; \
    /* P0: A k0 m0-3 + B k0; stage next A-k0/B-k0 */ \
    FRAG_A(a0, bufc, 0, 0); FRAG_B(b0, bufc, 0); \
    if ((T) < 3) { SCH((T)+1, 0); SCH((T)+1, 1); SCH((T)+1, 4); SCH((T)+1, 5); } \
    BAR(); WLGKM0(); \
    MFMA16(a0, b0, 0); \
    BAR(); \
    /* P1: A k0 m4-7 + B k1; stage next A-k1/B-k1 */ \
    FRAG_A(a1, bufc, 0, 4); FRAG_B(b1, bufc, 1); \
    if ((T) < 3) { SCH((T)+1, 2); SCH((T)+1, 3); SCH((T)+1, 6); SCH((T)+1, 7); } \
    BAR(); WLGKM0(); \
    MFMA16(a1, b0, 4); \
    BAR(); \
    /* P2: A k1 m0-3 */ \
    FRAG_A(a0, bufc, 1, 0); \
    BAR(); WLGKM0(); \
    MFMA16(a0, b1, 0); \
    BAR(); \
    /* P3: A k1 m4-7; gate next buffer */ \
    FRAG_A(a1, bufc, 1, 4); \
    BAR(); WLGKM0(); \
    MFMA16(a1, b1, 4); \
    if ((T) < 3) { WVM(0); } \
    BAR(); \
} while (0)

    f32x4 acc[8][4];
#pragma unroll
    for (int a = 0; a < 8; a++)
#pragma unroll
        for (int b = 0; b < 4; b++) acc[a][b] = (f32x4)0.f;

    // prologue: stage K-64 tile 0, drain, barrier
#pragma unroll
    for (int c = 0; c < 8; c++) SCH(0, c);
    WVM(0);
    BAR();

    KTILE(0);
    KTILE(1);
    KTILE(2);
    KTILE(3);

#undef KTILE
#undef MFMA16
#undef FRAG_A
#undef FRAG_B
#undef SCH

    // ================= epilogue: 2 rounds of (2 chunk-slots x 16 pairs) ====
    float* ps = (float*)sm;                       // [8][16][34] f32, overlays slot0
#pragma unroll
    for (int R = 0; R < 2; R++) {
        // ---- G writes: this round uses am = R*4 + a ----
#pragma unroll
        for (int a = 0; a < 4; a++) {
            const int am = R * 4 + a;
            const int lpr = ((a >> 1) & 1) * 8 + wc * 2;
            const int cs = ((a & 1) << 1) + (h4 >> 1);
#pragma unroll
            for (int bn = 0; bn < 4; bn++) {
                const int lp = lpr + (bn >> 1);
                const int e = ((bn & 1) << 4) + rl;
                unsigned int lo = (unsigned int)f2bf(acc[am][bn][0]) |
                                  ((unsigned int)f2bf(acc[am][bn][1]) << 16);
                unsigned int hi = (unsigned int)f2bf(acc[am][bn][2]) |
                                  ((unsigned int)f2bf(acc[am][bn][3]) << 16);
                u32x2 wv; wv[0] = lo; wv[1] = hi;
                *(u32x2*)(sm + wr * 33024 + lp * 2064 + e * 64 +
                          ((cs ^ (e & 3)) << 4) + ((h4 & 1) << 3)) = wv;
            }
        }
        WLGKM0();
        BAR();
        // ---- second GEMM: slot = wid>>2, K quarter = wid&3 ----
        const int slotR = wid >> 2, kq = wid & 3;
        f32x4 ae0 = (f32x4)0.f, ae1 = (f32x4)0.f;
        const char* grow = sm + slotR * 33024 + rl * 2064;
#pragma unroll
        for (int es = 0; es < 8; es++) {
            const int e = kq * 8 + es;
            bf16x8 ga = *(const bf16x8*)(grow + e * 64 + ((h4 ^ (e & 3)) << 4));
            bf16x8 wb0 = *(const bf16x8*)(Wt3 + (size_t)e * 1024 + rl * 32 + h4 * 8);
            bf16x8 wb1 = *(const bf16x8*)(Wt3 + (size_t)e * 1024 + (16 + rl) * 32 + h4 * 8);
            ae0 = __builtin_amdgcn_mfma_f32_16x16x32_bf16(ga, wb0, ae0, 0, 0, 0);
            ae1 = __builtin_amdgcn_mfma_f32_16x16x32_bf16(ga, wb1, ae1, 0, 0, 0);
        }
        WLGKM0();
        BAR();
        // ---- partials: ps[(slot*4+kq)][pair = h4*4+r][ch] (stride 34) ----
#pragma unroll
        for (int r = 0; r < 4; r++) {
            ps[((slotR * 4 + kq) * 16 + h4 * 4 + r) * 34 + rl]      = ae0[r];
            ps[((slotR * 4 + kq) * 16 + h4 * 4 + r) * 34 + 16 + rl] = ae1[r];
        }
        WLGKM0();
        BAR();
        // ---- reduce 4 K-quarters + bias + mask-norm + coalesced store ----
#pragma unroll
        for (int u = 0; u < 2; u++) {
            const int lp = (t >> 5) & 15, ch = t & 31;
            float v = 0.f;
#pragma unroll
            for (int k2 = 0; k2 < 4; k2++)
                v += ps[((u * 4 + k2) * 16 + lp) * 34 + ch];
            const int pi = u * 4 + R * 2 + (lp >> 3), pj = lp & 7;
            const int i = TI * 8 + pi, j = TJ * 8 + pj;
            out[((size_t)(i * N_RES + j)) * CCH + ch] =
                (v + bout[ch]) * inv_norm[(size_t)i * N_RES + j];
        }
        BAR();
    }
}

// ---------------------------------------------------------------------------
extern "C" void kernel_launch(void* const* d_in, const int* in_sizes, int n_in,
                              void* d_out, int out_size, void* d_ws, size_t ws_size,
                              hipStream_t stream)
{
    const float* m    = (const float*)d_in[0];
    const float* mask = (const float*)d_in[1];
    const float* gam  = (const float*)d_in[2];
    const float* bet  = (const float*)d_in[3];
    const float* Wa   = (const float*)d_in[4];
    const float* ba   = (const float*)d_in[5];
    const float* Wb   = (const float*)d_in[6];
    const float* bb   = (const float*)d_in[7];
    const float* Wout = (const float*)d_in[8];
    const float* bout = (const float*)d_in[9];
    float* out = (float*)d_out;

    char* ws = (char*)d_ws;
    char* Ag = ws;                                            //  8,388,608 B
    char* Bg = ws + 8388608;                                  //  8,388,608 B
    unsigned short* Wt3 = (unsigned short*)(ws + 16777216);   //     65,536 B
    float* inv_norm = (float*)(ws + 16842752);                //  1,048,576 B

    prep_ab<<<dim3(N_RES), dim3(256), 0, stream>>>(m, mask, gam, bet, Wa, ba, Wb, bb, Ag, Bg);
    kwt<<<dim3(128), dim3(256), 0, stream>>>(Wout, Wt3);
    knorm<<<dim3(64), dim3(256), 0, stream>>>(mask, inv_norm);
    kmain6<<<dim3(4096), dim3(512), 0, stream>>>(Ag, Bg, Wt3, inv_norm, bout, out);
}

// Round 7
// 210.445 us; speedup vs baseline: 1.1992x; 1.1992x over previous
//
#include <hip/hip_runtime.h>

#define S_SEQ 256
#define N_RES 512
#define CCH   32

typedef __attribute__((ext_vector_type(8))) short bf16x8;
typedef __attribute__((ext_vector_type(4))) float f32x4;
typedef __attribute__((ext_vector_type(2))) unsigned int u32x2;

__device__ __forceinline__ unsigned short f2bf(float x) {
    unsigned int u = __float_as_uint(x);
    return (unsigned short)((u + 0x7FFFu + ((u >> 16) & 1u)) >> 16);
}

#define GLOAD_LDS16(gp, lp) __builtin_amdgcn_global_load_lds( \
    (const __attribute__((address_space(1))) unsigned int*)(gp), \
    (__attribute__((address_space(3))) unsigned int*)(lp), 16, 0, 0)

#define BAR()    do { __builtin_amdgcn_s_barrier(); asm volatile("" ::: "memory"); } while (0)
#define WLGKM0() asm volatile("s_waitcnt lgkmcnt(0)" ::: "memory")
#define WVM(n)   asm volatile("s_waitcnt vmcnt(" #n ")" ::: "memory")

// ---------------------------------------------------------------------------
// Kernel 1: LayerNorm + dual projection + mask.
// A image (128-row tiles, 64B rows): byte = (i>>7)*65536 + kt*8192
//   + (ir=i&127)*64 + ((q ^ (ir&3))<<4)   [q = k-chunk of 8]
// B image (256-row tiles, 128B dual rows): byte = (j>>8)*131072 + kt*16384
//   + (ir=j&127)*128 + ((((j>>7)<<2)|q) ^ (ir&7))<<4
// Both linear-stageable via global_load_lds; frag reads conflict-free.
// ---------------------------------------------------------------------------
__global__ __launch_bounds__(256) void prep_ab(
    const float* __restrict__ m, const float* __restrict__ mask,
    const float* __restrict__ gam, const float* __restrict__ bet,
    const float* __restrict__ Wa, const float* __restrict__ ba,
    const float* __restrict__ Wb, const float* __restrict__ bb,
    char* __restrict__ Ag, char* __restrict__ Bg)
{
    __shared__ float WaL[1024], WbL[1024];
    __shared__ float gL[32], btL[32], baL[32], bbL[32];
    __shared__ unsigned short At[32 * 256];
    __shared__ unsigned short Bt[32 * 256];

    const int n = blockIdx.x;
    const int t = threadIdx.x;

    for (int i = t; i < 1024; i += 256) { WaL[i] = Wa[i]; WbL[i] = Wb[i]; }
    if (t < 32) { gL[t] = gam[t]; btL[t] = bet[t]; baL[t] = ba[t]; bbL[t] = bb[t]; }
    __syncthreads();

    const int s = t;
    float mv[32];
    const float* mrow = m + ((size_t)s * N_RES + n) * CCH;
#pragma unroll
    for (int c4 = 0; c4 < 8; c4++) {
        f32x4 v = *(const f32x4*)(mrow + c4 * 4);
        mv[c4 * 4 + 0] = v.x; mv[c4 * 4 + 1] = v.y;
        mv[c4 * 4 + 2] = v.z; mv[c4 * 4 + 3] = v.w;
    }
    float mu = 0.f;
#pragma unroll
    for (int c = 0; c < 32; c++) mu += mv[c];
    mu *= (1.f / 32.f);
    float var = 0.f;
#pragma unroll
    for (int c = 0; c < 32; c++) { float d = mv[c] - mu; var += d * d; }
    var *= (1.f / 32.f);
    float rs = rsqrtf(var + 1e-5f);
    float mh[32];
#pragma unroll
    for (int c = 0; c < 32; c++) mh[c] = (mv[c] - mu) * rs * gL[c] + btL[c];

    const float msk = mask[(size_t)s * N_RES + n];

    f32x4 av[8], bv[8];
#pragma unroll
    for (int cg = 0; cg < 8; cg++) { av[cg] = (f32x4)0.f; bv[cg] = (f32x4)0.f; }
#pragma unroll
    for (int k = 0; k < 32; k++) {
        float x = mh[k];
#pragma unroll
        for (int cg = 0; cg < 8; cg++) {
            f32x4 wa4 = *(const f32x4*)&WaL[k * 32 + cg * 4];
            f32x4 wb4 = *(const f32x4*)&WbL[k * 32 + cg * 4];
            av[cg] += x * wa4;
            bv[cg] += x * wb4;
        }
    }
#pragma unroll
    for (int cg = 0; cg < 8; cg++) {
#pragma unroll
        for (int u = 0; u < 4; u++) {
            int c = cg * 4 + u;
            At[c * 256 + s] = f2bf((av[cg][u] + baL[c]) * msk);
            Bt[c * 256 + s] = f2bf((bv[cg][u] + bbL[c]) * msk);
        }
    }
    __syncthreads();

    // flush both images (16B chunks). row index = n*32 + c.
    const size_t taA = (size_t)(n >> 2) * 65536;       // A tile = 128 rows
    const size_t taB = (size_t)(n >> 3) * 131072;      // B tile = 256 rows
    const int irb = (n & 3) * 32;                      // ir base (both: &127)
    const int halfB = (n >> 2) & 1;                    // B: row>>7
#pragma unroll
    for (int u = 0; u < 4; u++) {
        int cid = t * 4 + u;             // 1024 chunks: c (32) x 8-seq group g (32)
        int c = cid >> 5, g = cid & 31;
        int kt = g >> 2, q = g & 3;      // s = kt*32 + q*8 + j
        size_t offA = taA + (size_t)kt * 8192
                    + (size_t)(irb + c) * 64 + (size_t)((q ^ (c & 3)) << 4);
        size_t offB = taB + (size_t)kt * 16384
                    + (size_t)(irb + c) * 128
                    + (size_t)((((halfB << 2) | q) ^ (c & 7)) << 4);
        *(uint4*)(Ag + offA) = *(const uint4*)(At + c * 256 + g * 8);
        *(uint4*)(Bg + offB) = *(const uint4*)(Bt + c * 256 + g * 8);
    }
}

// ---------------------------------------------------------------------------
// Kernel 2: Wt3[e][ch][c] = bf16(Wout[(c*32+e)][ch])   (32 x 32 x 32 bf16)
// ---------------------------------------------------------------------------
__global__ __launch_bounds__(256) void kwt(const float* __restrict__ Wout,
                                           unsigned short* __restrict__ Wt3)
{
    int idx = blockIdx.x * 256 + threadIdx.x;   // 32768
    int e = idx >> 10, ch = (idx >> 5) & 31, c = idx & 31;
    Wt3[idx] = f2bf(Wout[(size_t)(c * 32 + e) * 32 + ch]);
}

// ---------------------------------------------------------------------------
// Kernel 3: inv_norm[i][j] = 1 / (sum_s mask[s,i]*mask[s,j] + 1e-3)
// ---------------------------------------------------------------------------
__global__ __launch_bounds__(256) void knorm(const float* __restrict__ mask,
                                             float* __restrict__ inv_norm)
{
    __shared__ float Mi[64][65];
    __shared__ float Mj[64][65];
    const int bi = blockIdx.x >> 3, bj = blockIdx.x & 7;
    const int t = threadIdx.x;
    const int ty = t >> 4, tx = t & 15;

    float acc[4][4];
#pragma unroll
    for (int a = 0; a < 4; a++)
#pragma unroll
        for (int b = 0; b < 4; b++) acc[a][b] = 0.f;

    for (int sc = 0; sc < 4; sc++) {
        for (int e = t; e < 4096; e += 256) {
            int sr = e >> 6, col = e & 63;
            Mi[sr][col] = mask[(size_t)(sc * 64 + sr) * N_RES + bi * 64 + col];
            Mj[sr][col] = mask[(size_t)(sc * 64 + sr) * N_RES + bj * 64 + col];
        }
        __syncthreads();
        for (int sp = 0; sp < 64; sp++) {
#pragma unroll
            for (int a = 0; a < 4; a++)
#pragma unroll
                for (int b = 0; b < 4; b++)
                    acc[a][b] += Mi[sp][ty * 4 + a] * Mj[sp][tx * 4 + b];
        }
        __syncthreads();
    }
#pragma unroll
    for (int a = 0; a < 4; a++)
#pragma unroll
        for (int b = 0; b < 4; b++) {
            int i = bi * 64 + ty * 4 + a;
            int j = bj * 64 + tx * 4 + b;
            inv_norm[(size_t)i * N_RES + j] = 1.f / (acc[a][b] + 1e-3f);
        }
}

// ---------------------------------------------------------------------------
// Kernel 7: 128x256 tile, 8 waves x (64x64), BK=32, dbuf 2x24KB, LDS 66048B
// -> 2 blocks/CU; __launch_bounds__(512,4) caps regs at 128 (acc=64).
// Counted schedule: vmcnt(3) keeps next KT's 3 loads in flight; 2 bar/KT.
// Epilogue: r5-verified structure, 32 pairs, single round.
// ---------------------------------------------------------------------------
__global__ __launch_bounds__(512, 4) void kmain7(
    const char* __restrict__ Ag, const char* __restrict__ Bg,
    const unsigned short* __restrict__ Wt3, const float* __restrict__ inv_norm,
    const float* __restrict__ bout, float* __restrict__ out)
{
    __shared__ __align__(16) char sm[66048];   // dbuf [0,49152); epi G 2x33024

    const int bid = blockIdx.x;                // 8192 = 128 TI x 64 TJ
    const int xcd = bid & 7;
    const int xidx = bid >> 3;                 // 0..1023
    const int chunk = xidx >> 8;               // 0..3
    const int TI = xcd * 16 + ((xidx >> 4) & 15);
    const int TJ = chunk * 16 + (xidx & 15);

    const int t = threadIdx.x;
    const int lane = t & 63, wid = t >> 6;
    const int wr = wid >> 2, wc = wid & 3;     // wave tile 64x64
    const int rl = lane & 15, h4 = lane >> 4;

    const char* pa = Ag + (size_t)TI * 65536;
    const char* pb = Bg + (size_t)TJ * 131072;

#define SH(kt) do { \
    char* db_ = sm + (((kt) & 1) * 24576); \
    GLOAD_LDS16(pa + (kt) * 8192 + t * 16,         db_ + t * 16); \
    GLOAD_LDS16(pb + (kt) * 16384 + t * 16,        db_ + 8192 + t * 16); \
    GLOAD_LDS16(pb + (kt) * 16384 + 8192 + t * 16, db_ + 16384 + t * 16); \
} while (0)

    // lane-constant frag offsets
    const int abase = (wr * 64 + rl) * 64 + ((h4 ^ (rl & 3)) << 4);          // + am*1024
    const int bbase = 8192 + ((wc & 1) * 64 + rl) * 128
                    + (((((wc >> 1) << 2) | h4) ^ (rl & 7)) << 4);           // + bn*2048

    f32x4 acc[4][4];
#pragma unroll
    for (int a = 0; a < 4; a++)
#pragma unroll
        for (int b = 0; b < 4; b++) acc[a][b] = (f32x4)0.f;

    SH(0);
    SH(1);

#pragma unroll
    for (int kt = 0; kt < 8; kt++) {
        if (kt < 7) { WVM(3); } else { WVM(0); }
        BAR();                                 // kt's data visible to all waves
        const char* buf = sm + ((kt & 1) * 24576);
        bf16x8 af[4], bfr[4];
#pragma unroll
        for (int am = 0; am < 4; am++)
            af[am] = *(const bf16x8*)(buf + abase + am * 1024);
#pragma unroll
        for (int bn = 0; bn < 4; bn++)
            bfr[bn] = *(const bf16x8*)(buf + bbase + bn * 2048);
        WLGKM0();
        __builtin_amdgcn_s_setprio(1);
#pragma unroll
        for (int am = 0; am < 4; am++)
#pragma unroll
            for (int bn = 0; bn < 4; bn++)
                acc[am][bn] = __builtin_amdgcn_mfma_f32_16x16x32_bf16(
                    af[am], bfr[bn], acc[am][bn], 0, 0, 0);
        __builtin_amdgcn_s_setprio(0);
        BAR();                                 // all waves' reads retired
        if (kt <= 5) SH(kt + 2);               // safe: overwrites kt's buffer
    }
#undef SH

    // ---- epilogue: G write (32 pairs, 2 slots x 16), conflict-layout r5 ----
#pragma unroll
    for (int am = 0; am < 4; am++) {
        const int lpr = (am >> 1) * 8 + wc * 2;
        const int cs = ((am & 1) << 1) + (h4 >> 1);
#pragma unroll
        for (int bn = 0; bn < 4; bn++) {
            const int lp = lpr + (bn >> 1);
            const int e = ((bn & 1) << 4) + rl;
            unsigned int lo = (unsigned int)f2bf(acc[am][bn][0]) |
                              ((unsigned int)f2bf(acc[am][bn][1]) << 16);
            unsigned int hi = (unsigned int)f2bf(acc[am][bn][2]) |
                              ((unsigned int)f2bf(acc[am][bn][3]) << 16);
            u32x2 wv; wv[0] = lo; wv[1] = hi;
            *(u32x2*)(sm + wr * 33024 + lp * 2064 + e * 64 +
                      ((cs ^ (e & 3)) << 4) + ((h4 & 1) << 3)) = wv;
        }
    }
    WLGKM0();
    BAR();

    // ---- second GEMM: slot = wid>>2 (16 pairs), K quarter = wid&3 ----
    const int slotR = wid >> 2, kq = wid & 3;
    f32x4 ae0 = (f32x4)0.f, ae1 = (f32x4)0.f;
    const char* grow = sm + slotR * 33024 + rl * 2064;
#pragma unroll
    for (int es = 0; es < 8; es++) {
        const int e = kq * 8 + es;
        bf16x8 ga = *(const bf16x8*)(grow + e * 64 + ((h4 ^ (e & 3)) << 4));
        bf16x8 wb0 = *(const bf16x8*)(Wt3 + (size_t)e * 1024 + rl * 32 + h4 * 8);
        bf16x8 wb1 = *(const bf16x8*)(Wt3 + (size_t)e * 1024 + (16 + rl) * 32 + h4 * 8);
        ae0 = __builtin_amdgcn_mfma_f32_16x16x32_bf16(ga, wb0, ae0, 0, 0, 0);
        ae1 = __builtin_amdgcn_mfma_f32_16x16x32_bf16(ga, wb1, ae1, 0, 0, 0);
    }
    WLGKM0();
    BAR();

    // ---- partials ps[(slot*4+kq)][pair=h4*4+r][ch] (stride 34) ----
    float* ps = (float*)sm;
#pragma unroll
    for (int r = 0; r < 4; r++) {
        ps[((slotR * 4 + kq) * 16 + h4 * 4 + r) * 34 + rl]      = ae0[r];
        ps[((slotR * 4 + kq) * 16 + h4 * 4 + r) * 34 + 16 + rl] = ae1[r];
    }
    WLGKM0();
    BAR();

    // ---- reduce 4 K-quarters + bias + mask-norm + coalesced store ----
#pragma unroll
    for (int u = 0; u < 2; u++) {
        const int idx = u * 512 + t;
        const int p = idx >> 5, ch = idx & 31;
        float v = 0.f;
#pragma unroll
        for (int k2 = 0; k2 < 4; k2++)
            v += ps[(((p >> 4) * 4 + k2) * 16 + (p & 15)) * 34 + ch];
        const int i = TI * 4 + (p >> 3), j = TJ * 8 + (p & 7);
        out[((size_t)(i * N_RES + j)) * CCH + ch] =
            (v + bout[ch]) * inv_norm[(size_t)i * N_RES + j];
    }
}

// ---------------------------------------------------------------------------
extern "C" void kernel_launch(void* const* d_in, const int* in_sizes, int n_in,
                              void* d_out, int out_size, void* d_ws, size_t ws_size,
                              hipStream_t stream)
{
    const float* m    = (const float*)d_in[0];
    const float* mask = (const float*)d_in[1];
    const float* gam  = (const float*)d_in[2];
    const float* bet  = (const float*)d_in[3];
    const float* Wa   = (const float*)d_in[4];
    const float* ba   = (const float*)d_in[5];
    const float* Wb   = (const float*)d_in[6];
    const float* bb   = (const float*)d_in[7];
    const float* Wout = (const float*)d_in[8];
    const float* bout = (const float*)d_in[9];
    float* out = (float*)d_out;

    char* ws = (char*)d_ws;
    char* Ag = ws;                                            //  8,388,608 B
    char* Bg = ws + 8388608;                                  //  8,388,608 B
    unsigned short* Wt3 = (unsigned short*)(ws + 16777216);   //     65,536 B
    float* inv_norm = (float*)(ws + 16842752);                //  1,048,576 B

    prep_ab<<<dim3(N_RES), dim3(256), 0, stream>>>(m, mask, gam, bet, Wa, ba, Wb, bb, Ag, Bg);
    kwt<<<dim3(128), dim3(256), 0, stream>>>(Wout, Wt3);
    knorm<<<dim3(64), dim3(256), 0, stream>>>(mask, inv_norm);
    kmain7<<<dim3(8192), dim3(512), 0, stream>>>(Ag, Bg, Wt3, inv_norm, bout, out);
}

// Round 8
// 205.420 us; speedup vs baseline: 1.2286x; 1.0245x over previous
//
#include <hip/hip_runtime.h>

#define S_SEQ 256
#define N_RES 512
#define CCH   32

typedef __attribute__((ext_vector_type(8))) short bf16x8;
typedef __attribute__((ext_vector_type(4))) float f32x4;
typedef __attribute__((ext_vector_type(2))) unsigned int u32x2;

__device__ __forceinline__ unsigned short f2bf(float x) {
    unsigned int u = __float_as_uint(x);
    return (unsigned short)((u + 0x7FFFu + ((u >> 16) & 1u)) >> 16);
}

#define GLOAD_LDS16(gp, lp) __builtin_amdgcn_global_load_lds( \
    (const __attribute__((address_space(1))) unsigned int*)(gp), \
    (__attribute__((address_space(3))) unsigned int*)(lp), 16, 0, 0)

#define BAR()    do { __builtin_amdgcn_s_barrier(); asm volatile("" ::: "memory"); } while (0)
#define WLGKM0() asm volatile("s_waitcnt lgkmcnt(0)" ::: "memory")
#define WVM(n)   asm volatile("s_waitcnt vmcnt(" #n ")" ::: "memory")

// ---------------------------------------------------------------------------
// Kernel 1: LayerNorm + dual projection + mask. A and B both written as the
// SAME dual-row 128B-row image over 128-row tiles (conflict-free for b128
// frag reads; 2 lanes/bank-quad per 16-lane phase):
//   row = n*32+c (tile = row>>7); r = row&127; half = r>>6; ir = r&63
//   byte = (row>>7)*65536 + kt*8192 + ir*128 + ((((half<<2)|q) ^ (ir&7))<<4)
//   (kt = s-tile of 32, q = s-chunk of 8)
// ---------------------------------------------------------------------------
__global__ __launch_bounds__(256) void prep_ab(
    const float* __restrict__ m, const float* __restrict__ mask,
    const float* __restrict__ gam, const float* __restrict__ bet,
    const float* __restrict__ Wa, const float* __restrict__ ba,
    const float* __restrict__ Wb, const float* __restrict__ bb,
    char* __restrict__ Ag, char* __restrict__ Bg)
{
    __shared__ float WaL[1024], WbL[1024];
    __shared__ float gL[32], btL[32], baL[32], bbL[32];
    __shared__ unsigned short At[32 * 256];
    __shared__ unsigned short Bt[32 * 256];

    const int n = blockIdx.x;
    const int t = threadIdx.x;

    for (int i = t; i < 1024; i += 256) { WaL[i] = Wa[i]; WbL[i] = Wb[i]; }
    if (t < 32) { gL[t] = gam[t]; btL[t] = bet[t]; baL[t] = ba[t]; bbL[t] = bb[t]; }
    __syncthreads();

    const int s = t;
    float mv[32];
    const float* mrow = m + ((size_t)s * N_RES + n) * CCH;
#pragma unroll
    for (int c4 = 0; c4 < 8; c4++) {
        f32x4 v = *(const f32x4*)(mrow + c4 * 4);
        mv[c4 * 4 + 0] = v.x; mv[c4 * 4 + 1] = v.y;
        mv[c4 * 4 + 2] = v.z; mv[c4 * 4 + 3] = v.w;
    }
    float mu = 0.f;
#pragma unroll
    for (int c = 0; c < 32; c++) mu += mv[c];
    mu *= (1.f / 32.f);
    float var = 0.f;
#pragma unroll
    for (int c = 0; c < 32; c++) { float d = mv[c] - mu; var += d * d; }
    var *= (1.f / 32.f);
    float rs = rsqrtf(var + 1e-5f);
    float mh[32];
#pragma unroll
    for (int c = 0; c < 32; c++) mh[c] = (mv[c] - mu) * rs * gL[c] + btL[c];

    const float msk = mask[(size_t)s * N_RES + n];

    f32x4 av[8], bv[8];
#pragma unroll
    for (int cg = 0; cg < 8; cg++) { av[cg] = (f32x4)0.f; bv[cg] = (f32x4)0.f; }
#pragma unroll
    for (int k = 0; k < 32; k++) {
        float x = mh[k];
#pragma unroll
        for (int cg = 0; cg < 8; cg++) {
            f32x4 wa4 = *(const f32x4*)&WaL[k * 32 + cg * 4];
            f32x4 wb4 = *(const f32x4*)&WbL[k * 32 + cg * 4];
            av[cg] += x * wa4;
            bv[cg] += x * wb4;
        }
    }
#pragma unroll
    for (int cg = 0; cg < 8; cg++) {
#pragma unroll
        for (int u = 0; u < 4; u++) {
            int c = cg * 4 + u;
            At[c * 256 + s] = f2bf((av[cg][u] + baL[c]) * msk);
            Bt[c * 256 + s] = f2bf((bv[cg][u] + bbL[c]) * msk);
        }
    }
    __syncthreads();

    // flush (16B chunks): row = n*32+c
    const size_t tbase = (size_t)(n >> 2) * 65536;     // tile = 128 rows
    const int halfq = ((n >> 1) & 1) << 2;             // (row>>6)&1 <<2
    const int irb = (n & 1) * 32;                      // ir = (row&63) base
#pragma unroll
    for (int u = 0; u < 4; u++) {
        int cid = t * 4 + u;             // 1024 chunks: c (32) x 8-seq group g (32)
        int c = cid >> 5, g = cid & 31;
        int kt = g >> 2, q = g & 3;      // s = kt*32 + q*8 + j
        size_t off = tbase + (size_t)kt * 8192 + (size_t)(irb + c) * 128
                   + (size_t)(((halfq | q) ^ (c & 7)) << 4);
        *(uint4*)(Ag + off) = *(const uint4*)(At + c * 256 + g * 8);
        *(uint4*)(Bg + off) = *(const uint4*)(Bt + c * 256 + g * 8);
    }
}

// ---------------------------------------------------------------------------
// Kernel 2: Wt3[e][ch][c] = bf16(Wout[(c*32+e)][ch])   (32 x 32 x 32 bf16)
// ---------------------------------------------------------------------------
__global__ __launch_bounds__(256) void kwt(const float* __restrict__ Wout,
                                           unsigned short* __restrict__ Wt3)
{
    int idx = blockIdx.x * 256 + threadIdx.x;   // 32768
    int e = idx >> 10, ch = (idx >> 5) & 31, c = idx & 31;
    Wt3[idx] = f2bf(Wout[(size_t)(c * 32 + e) * 32 + ch]);
}

// ---------------------------------------------------------------------------
// Kernel 3: inv_norm[i][j] = 1 / (sum_s mask[s,i]*mask[s,j] + 1e-3)
// ---------------------------------------------------------------------------
__global__ __launch_bounds__(256) void knorm(const float* __restrict__ mask,
                                             float* __restrict__ inv_norm)
{
    __shared__ float Mi[64][65];
    __shared__ float Mj[64][65];
    const int bi = blockIdx.x >> 3, bj = blockIdx.x & 7;
    const int t = threadIdx.x;
    const int ty = t >> 4, tx = t & 15;

    float acc[4][4];
#pragma unroll
    for (int a = 0; a < 4; a++)
#pragma unroll
        for (int b = 0; b < 4; b++) acc[a][b] = 0.f;

    for (int sc = 0; sc < 4; sc++) {
        for (int e = t; e < 4096; e += 256) {
            int sr = e >> 6, col = e & 63;
            Mi[sr][col] = mask[(size_t)(sc * 64 + sr) * N_RES + bi * 64 + col];
            Mj[sr][col] = mask[(size_t)(sc * 64 + sr) * N_RES + bj * 64 + col];
        }
        __syncthreads();
        for (int sp = 0; sp < 64; sp++) {
#pragma unroll
            for (int a = 0; a < 4; a++)
#pragma unroll
                for (int b = 0; b < 4; b++)
                    acc[a][b] += Mi[sp][ty * 4 + a] * Mj[sp][tx * 4 + b];
        }
        __syncthreads();
    }
#pragma unroll
    for (int a = 0; a < 4; a++)
#pragma unroll
        for (int b = 0; b < 4; b++) {
            int i = bi * 64 + ty * 4 + a;
            int j = bj * 64 + tx * 4 + b;
            inv_norm[(size_t)i * N_RES + j] = 1.f / (acc[a][b] + 1e-3f);
        }
}

// ---------------------------------------------------------------------------
// Kernel 8: 128x128 tile, 4 waves x (64x64), BK=32, dbuf 2x16KB, LDS 33KB
// -> 4 blocks/CU (16 waves, 4 independent streams). Counted vmcnt(4).
// Both A and B frag reads conflict-free (dual-row 128B image).
// Epilogue: 16 pairs -> G (33KB, overlays staging) -> MFMA vs Wt3 (K split
// 4 ways across waves) -> ps overlays G head -> reduce + bias + norm.
// ---------------------------------------------------------------------------
__global__ __launch_bounds__(256, 4) void kmain8(
    const char* __restrict__ Ag, const char* __restrict__ Bg,
    const unsigned short* __restrict__ Wt3, const float* __restrict__ inv_norm,
    const float* __restrict__ bout, float* __restrict__ out)
{
    __shared__ __align__(16) char sm[33024];   // dbuf [0,32768); epi G [0,33024)

    const int bid = blockIdx.x;                // 16384 = 128 TI x 128 TJ
    const int xcd = bid & 7;
    const int xidx = bid >> 3;                 // 0..2047
    const int TI = xcd * 16 + ((xidx >> 5) & 15);
    const int TJ = (xidx >> 9) * 32 + (xidx & 31);

    const int t = threadIdx.x;
    const int lane = t & 63, wid = t >> 6;
    const int wr = wid >> 1, wc = wid & 1;     // wave tile 64x64
    const int rl = lane & 15, h4 = lane >> 4;

    const char* pa = Ag + (size_t)TI * 65536;
    const char* pb = Bg + (size_t)TJ * 65536;

#define SH(kt) do { \
    char* db_ = sm + (((kt) & 1) * 16384); \
    GLOAD_LDS16(pa + (kt) * 8192 + t * 16,        db_ + t * 16); \
    GLOAD_LDS16(pa + (kt) * 8192 + 4096 + t * 16, db_ + 4096 + t * 16); \
    GLOAD_LDS16(pb + (kt) * 8192 + t * 16,        db_ + 8192 + t * 16); \
    GLOAD_LDS16(pb + (kt) * 8192 + 4096 + t * 16, db_ + 12288 + t * 16); \
} while (0)

    // lane-constant frag offsets (dual-row image: half = wr / wc)
    const int abase = rl * 128 + (((((wr << 2) | h4)) ^ (rl & 7)) << 4);        // + am*2048
    const int bbase = 8192 + rl * 128 + (((((wc << 2) | h4)) ^ (rl & 7)) << 4); // + bn*2048

    f32x4 acc[4][4];
#pragma unroll
    for (int a = 0; a < 4; a++)
#pragma unroll
        for (int b = 0; b < 4; b++) acc[a][b] = (f32x4)0.f;

    SH(0);
    SH(1);

#pragma unroll
    for (int kt = 0; kt < 8; kt++) {
        if (kt < 7) { WVM(4); } else { WVM(0); }
        BAR();                                 // kt's data visible to all waves
        const char* buf = sm + ((kt & 1) * 16384);
        bf16x8 af[4], bfr[4];
#pragma unroll
        for (int am = 0; am < 4; am++)
            af[am] = *(const bf16x8*)(buf + abase + am * 2048);
#pragma unroll
        for (int bn = 0; bn < 4; bn++)
            bfr[bn] = *(const bf16x8*)(buf + bbase + bn * 2048);
        WLGKM0();
        __builtin_amdgcn_s_setprio(1);
#pragma unroll
        for (int am = 0; am < 4; am++)
#pragma unroll
            for (int bn = 0; bn < 4; bn++)
                acc[am][bn] = __builtin_amdgcn_mfma_f32_16x16x32_bf16(
                    af[am], bfr[bn], acc[am][bn], 0, 0, 0);
        __builtin_amdgcn_s_setprio(0);
        BAR();                                 // all waves' reads retired
        if (kt <= 5) SH(kt + 2);               // safe: overwrites kt's buffer
    }
#undef SH

    // ---- epilogue: G write (16 pairs x 2064B, 16B-XOR layout) ----
#pragma unroll
    for (int am = 0; am < 4; am++) {
        const int cs = ((am & 1) << 1) + (h4 >> 1);
#pragma unroll
        for (int bn = 0; bn < 4; bn++) {
            const int p = (wr * 2 + (am >> 1)) * 4 + wc * 2 + (bn >> 1);
            const int e = ((bn & 1) << 4) + rl;
            unsigned int lo = (unsigned int)f2bf(acc[am][bn][0]) |
                              ((unsigned int)f2bf(acc[am][bn][1]) << 16);
            unsigned int hi = (unsigned int)f2bf(acc[am][bn][2]) |
                              ((unsigned int)f2bf(acc[am][bn][3]) << 16);
            u32x2 wv; wv[0] = lo; wv[1] = hi;
            *(u32x2*)(sm + p * 2064 + e * 64 +
                      ((cs ^ (e & 3)) << 4) + ((h4 & 1) << 3)) = wv;
        }
    }
    WLGKM0();
    BAR();

    // ---- second GEMM: wave = K quarter kq; 16 pairs x 32 ch each ----
    const int kq = wid;
    f32x4 ae0 = (f32x4)0.f, ae1 = (f32x4)0.f;
    const char* grow = sm + rl * 2064;
#pragma unroll
    for (int es = 0; es < 8; es++) {
        const int e = kq * 8 + es;
        bf16x8 ga = *(const bf16x8*)(grow + e * 64 + ((h4 ^ (e & 3)) << 4));
        bf16x8 wb0 = *(const bf16x8*)(Wt3 + (size_t)e * 1024 + rl * 32 + h4 * 8);
        bf16x8 wb1 = *(const bf16x8*)(Wt3 + (size_t)e * 1024 + (16 + rl) * 32 + h4 * 8);
        ae0 = __builtin_amdgcn_mfma_f32_16x16x32_bf16(ga, wb0, ae0, 0, 0, 0);
        ae1 = __builtin_amdgcn_mfma_f32_16x16x32_bf16(ga, wb1, ae1, 0, 0, 0);
    }
    WLGKM0();
    BAR();                                     // all ga reads done -> reuse G head

    // ---- partials ps[kq][pair=h4*4+r][ch] (stride 34), overlays G[0,8704) ----
    float* ps = (float*)sm;
#pragma unroll
    for (int r = 0; r < 4; r++) {
        ps[(kq * 16 + h4 * 4 + r) * 34 + rl]      = ae0[r];
        ps[(kq * 16 + h4 * 4 + r) * 34 + 16 + rl] = ae1[r];
    }
    WLGKM0();
    BAR();

    // ---- reduce 4 K-quarters + bias + mask-norm + coalesced store ----
#pragma unroll
    for (int u = 0; u < 2; u++) {
        const int idx = u * 256 + t;
        const int p = idx >> 5, ch = idx & 31;
        float v = 0.f;
#pragma unroll
        for (int k2 = 0; k2 < 4; k2++)
            v += ps[(k2 * 16 + p) * 34 + ch];
        const int i = TI * 4 + (p >> 2), j = TJ * 4 + (p & 3);
        out[((size_t)(i * N_RES + j)) * CCH + ch] =
            (v + bout[ch]) * inv_norm[(size_t)i * N_RES + j];
    }
}

// ---------------------------------------------------------------------------
extern "C" void kernel_launch(void* const* d_in, const int* in_sizes, int n_in,
                              void* d_out, int out_size, void* d_ws, size_t ws_size,
                              hipStream_t stream)
{
    const float* m    = (const float*)d_in[0];
    const float* mask = (const float*)d_in[1];
    const float* gam  = (const float*)d_in[2];
    const float* bet  = (const float*)d_in[3];
    const float* Wa   = (const float*)d_in[4];
    const float* ba   = (const float*)d_in[5];
    const float* Wb   = (const float*)d_in[6];
    const float* bb   = (const float*)d_in[7];
    const float* Wout = (const float*)d_in[8];
    const float* bout = (const float*)d_in[9];
    float* out = (float*)d_out;

    char* ws = (char*)d_ws;
    char* Ag = ws;                                            //  8,388,608 B
    char* Bg = ws + 8388608;                                  //  8,388,608 B
    unsigned short* Wt3 = (unsigned short*)(ws + 16777216);   //     65,536 B
    float* inv_norm = (float*)(ws + 16842752);                //  1,048,576 B

    prep_ab<<<dim3(N_RES), dim3(256), 0, stream>>>(m, mask, gam, bet, Wa, ba, Wb, bb, Ag, Bg);
    kwt<<<dim3(128), dim3(256), 0, stream>>>(Wout, Wt3);
    knorm<<<dim3(64), dim3(256), 0, stream>>>(mask, inv_norm);
    kmain8<<<dim3(16384), dim3(256), 0, stream>>>(Ag, Bg, Wt3, inv_norm, bout, out);
}

// Round 9
// 201.971 us; speedup vs baseline: 1.2495x; 1.0171x over previous
//
#include <hip/hip_runtime.h>

#define S_SEQ 256
#define N_RES 512
#define CCH   32

typedef __attribute__((ext_vector_type(8))) short bf16x8;
typedef __attribute__((ext_vector_type(4))) float f32x4;
typedef __attribute__((ext_vector_type(2))) unsigned int u32x2;

__device__ __forceinline__ unsigned short f2bf(float x) {
    unsigned int u = __float_as_uint(x);
    return (unsigned short)((u + 0x7FFFu + ((u >> 16) & 1u)) >> 16);
}

#define GLOAD_LDS16(gp, lp) __builtin_amdgcn_global_load_lds( \
    (const __attribute__((address_space(1))) unsigned int*)(gp), \
    (__attribute__((address_space(3))) unsigned int*)(lp), 16, 0, 0)

#define BAR()    do { __builtin_amdgcn_s_barrier(); asm volatile("" ::: "memory"); } while (0)
#define WLGKM0() asm volatile("s_waitcnt lgkmcnt(0)" ::: "memory")
#define WVM(n)   asm volatile("s_waitcnt vmcnt(" #n ")" ::: "memory")

// ---------------------------------------------------------------------------
// Kernel 1: LayerNorm + dual projection + mask. A and B both written as the
// dual-row 128B-row image over 128-row tiles (conflict-free b128 frag reads):
//   row = n*32+c (tile = row>>7); r = row&127; half = r>>6; ir = r&63
//   byte = (row>>7)*65536 + kt*8192 + ir*128 + ((((half<<2)|q) ^ (ir&7))<<4)
// ---------------------------------------------------------------------------
__global__ __launch_bounds__(256) void prep_ab(
    const float* __restrict__ m, const float* __restrict__ mask,
    const float* __restrict__ gam, const float* __restrict__ bet,
    const float* __restrict__ Wa, const float* __restrict__ ba,
    const float* __restrict__ Wb, const float* __restrict__ bb,
    char* __restrict__ Ag, char* __restrict__ Bg)
{
    __shared__ float WaL[1024], WbL[1024];
    __shared__ float gL[32], btL[32], baL[32], bbL[32];
    __shared__ unsigned short At[32 * 256];
    __shared__ unsigned short Bt[32 * 256];

    const int n = blockIdx.x;
    const int t = threadIdx.x;

    for (int i = t; i < 1024; i += 256) { WaL[i] = Wa[i]; WbL[i] = Wb[i]; }
    if (t < 32) { gL[t] = gam[t]; btL[t] = bet[t]; baL[t] = ba[t]; bbL[t] = bb[t]; }
    __syncthreads();

    const int s = t;
    float mv[32];
    const float* mrow = m + ((size_t)s * N_RES + n) * CCH;
#pragma unroll
    for (int c4 = 0; c4 < 8; c4++) {
        f32x4 v = *(const f32x4*)(mrow + c4 * 4);
        mv[c4 * 4 + 0] = v.x; mv[c4 * 4 + 1] = v.y;
        mv[c4 * 4 + 2] = v.z; mv[c4 * 4 + 3] = v.w;
    }
    float mu = 0.f;
#pragma unroll
    for (int c = 0; c < 32; c++) mu += mv[c];
    mu *= (1.f / 32.f);
    float var = 0.f;
#pragma unroll
    for (int c = 0; c < 32; c++) { float d = mv[c] - mu; var += d * d; }
    var *= (1.f / 32.f);
    float rs = rsqrtf(var + 1e-5f);
    float mh[32];
#pragma unroll
    for (int c = 0; c < 32; c++) mh[c] = (mv[c] - mu) * rs * gL[c] + btL[c];

    const float msk = mask[(size_t)s * N_RES + n];

    f32x4 av[8], bv[8];
#pragma unroll
    for (int cg = 0; cg < 8; cg++) { av[cg] = (f32x4)0.f; bv[cg] = (f32x4)0.f; }
#pragma unroll
    for (int k = 0; k < 32; k++) {
        float x = mh[k];
#pragma unroll
        for (int cg = 0; cg < 8; cg++) {
            f32x4 wa4 = *(const f32x4*)&WaL[k * 32 + cg * 4];
            f32x4 wb4 = *(const f32x4*)&WbL[k * 32 + cg * 4];
            av[cg] += x * wa4;
            bv[cg] += x * wb4;
        }
    }
#pragma unroll
    for (int cg = 0; cg < 8; cg++) {
#pragma unroll
        for (int u = 0; u < 4; u++) {
            int c = cg * 4 + u;
            At[c * 256 + s] = f2bf((av[cg][u] + baL[c]) * msk);
            Bt[c * 256 + s] = f2bf((bv[cg][u] + bbL[c]) * msk);
        }
    }
    __syncthreads();

    // flush (16B chunks): row = n*32+c
    const size_t tbase = (size_t)(n >> 2) * 65536;     // tile = 128 rows
    const int halfq = ((n >> 1) & 1) << 2;             // (row>>6)&1 <<2
    const int irb = (n & 1) * 32;                      // ir = (row&63) base
#pragma unroll
    for (int u = 0; u < 4; u++) {
        int cid = t * 4 + u;             // 1024 chunks: c (32) x 8-seq group g (32)
        int c = cid >> 5, g = cid & 31;
        int kt = g >> 2, q = g & 3;      // s = kt*32 + q*8 + j
        size_t off = tbase + (size_t)kt * 8192 + (size_t)(irb + c) * 128
                   + (size_t)(((halfq | q) ^ (c & 7)) << 4);
        *(uint4*)(Ag + off) = *(const uint4*)(At + c * 256 + g * 8);
        *(uint4*)(Bg + off) = *(const uint4*)(Bt + c * 256 + g * 8);
    }
}

// ---------------------------------------------------------------------------
// Kernel 2: Wt3[e][ch][c] = bf16(Wout[(c*32+e)][ch])   (32 x 32 x 32 bf16)
// ---------------------------------------------------------------------------
__global__ __launch_bounds__(256) void kwt(const float* __restrict__ Wout,
                                           unsigned short* __restrict__ Wt3)
{
    int idx = blockIdx.x * 256 + threadIdx.x;   // 32768
    int e = idx >> 10, ch = (idx >> 5) & 31, c = idx & 31;
    Wt3[idx] = f2bf(Wout[(size_t)(c * 32 + e) * 32 + ch]);
}

// ---------------------------------------------------------------------------
// Kernel 3: inv_norm[i][j] = 1 / (sum_s mask[s,i]*mask[s,j] + 1e-3)
// ---------------------------------------------------------------------------
__global__ __launch_bounds__(256) void knorm(const float* __restrict__ mask,
                                             float* __restrict__ inv_norm)
{
    __shared__ float Mi[64][65];
    __shared__ float Mj[64][65];
    const int bi = blockIdx.x >> 3, bj = blockIdx.x & 7;
    const int t = threadIdx.x;
    const int ty = t >> 4, tx = t & 15;

    float acc[4][4];
#pragma unroll
    for (int a = 0; a < 4; a++)
#pragma unroll
        for (int b = 0; b < 4; b++) acc[a][b] = 0.f;

    for (int sc = 0; sc < 4; sc++) {
        for (int e = t; e < 4096; e += 256) {
            int sr = e >> 6, col = e & 63;
            Mi[sr][col] = mask[(size_t)(sc * 64 + sr) * N_RES + bi * 64 + col];
            Mj[sr][col] = mask[(size_t)(sc * 64 + sr) * N_RES + bj * 64 + col];
        }
        __syncthreads();
        for (int sp = 0; sp < 64; sp++) {
#pragma unroll
            for (int a = 0; a < 4; a++)
#pragma unroll
                for (int b = 0; b < 4; b++)
                    acc[a][b] += Mi[sp][ty * 4 + a] * Mj[sp][tx * 4 + b];
        }
        __syncthreads();
    }
#pragma unroll
    for (int a = 0; a < 4; a++)
#pragma unroll
        for (int b = 0; b < 4; b++) {
            int i = bi * 64 + ty * 4 + a;
            int j = bj * 64 + tx * 4 + b;
            inv_norm[(size_t)i * N_RES + j] = 1.f / (acc[a][b] + 1e-3f);
        }
}

// ---------------------------------------------------------------------------
// Kernel 9: r8 structure (128x128 tile, 4 waves, dbuf 2x16KB, 4 blocks/CU,
// counted vmcnt(4)) with: (a) no forced lgkm drain in the main loop — the
// compiler emits counted lgkmcnt so MFMA starts before all 8 frags land;
// (b) G swizzle f(e) = (e>>1)&3 on BOTH sides -> G writes 2-way (free)
// instead of 4-way; (c) epilogue drains trimmed to the two write-visibility
// points only.
// ---------------------------------------------------------------------------
__global__ __launch_bounds__(256, 4) void kmain9(
    const char* __restrict__ Ag, const char* __restrict__ Bg,
    const unsigned short* __restrict__ Wt3, const float* __restrict__ inv_norm,
    const float* __restrict__ bout, float* __restrict__ out)
{
    __shared__ __align__(16) char sm[33024];   // dbuf [0,32768); epi G [0,33024)

    const int bid = blockIdx.x;                // 16384 = 128 TI x 128 TJ
    const int xcd = bid & 7;
    const int xidx = bid >> 3;                 // 0..2047
    const int TI = xcd * 16 + ((xidx >> 5) & 15);
    const int TJ = (xidx >> 9) * 32 + (xidx & 31);

    const int t = threadIdx.x;
    const int lane = t & 63, wid = t >> 6;
    const int wr = wid >> 1, wc = wid & 1;     // wave tile 64x64
    const int rl = lane & 15, h4 = lane >> 4;

    const char* pa = Ag + (size_t)TI * 65536;
    const char* pb = Bg + (size_t)TJ * 65536;

#define SH(kt) do { \
    char* db_ = sm + (((kt) & 1) * 16384); \
    GLOAD_LDS16(pa + (kt) * 8192 + t * 16,        db_ + t * 16); \
    GLOAD_LDS16(pa + (kt) * 8192 + 4096 + t * 16, db_ + 4096 + t * 16); \
    GLOAD_LDS16(pb + (kt) * 8192 + t * 16,        db_ + 8192 + t * 16); \
    GLOAD_LDS16(pb + (kt) * 8192 + 4096 + t * 16, db_ + 12288 + t * 16); \
} while (0)

    // lane-constant frag offsets (dual-row image: half = wr / wc)
    const int abase = rl * 128 + (((((wr << 2) | h4)) ^ (rl & 7)) << 4);        // + am*2048
    const int bbase = 8192 + rl * 128 + (((((wc << 2) | h4)) ^ (rl & 7)) << 4); // + bn*2048

    f32x4 acc[4][4];
#pragma unroll
    for (int a = 0; a < 4; a++)
#pragma unroll
        for (int b = 0; b < 4; b++) acc[a][b] = (f32x4)0.f;

    SH(0);
    SH(1);

#pragma unroll
    for (int kt = 0; kt < 8; kt++) {
        if (kt < 7) { WVM(4); } else { WVM(0); }
        BAR();                                 // kt's data visible to all waves
        const char* buf = sm + ((kt & 1) * 16384);
        bf16x8 af[4], bfr[4];
#pragma unroll
        for (int am = 0; am < 4; am++)
            af[am] = *(const bf16x8*)(buf + abase + am * 2048);
#pragma unroll
        for (int bn = 0; bn < 4; bn++)
            bfr[bn] = *(const bf16x8*)(buf + bbase + bn * 2048);
        __builtin_amdgcn_s_setprio(1);
#pragma unroll
        for (int am = 0; am < 4; am++)
#pragma unroll
            for (int bn = 0; bn < 4; bn++)
                acc[am][bn] = __builtin_amdgcn_mfma_f32_16x16x32_bf16(
                    af[am], bfr[bn], acc[am][bn], 0, 0, 0);
        __builtin_amdgcn_s_setprio(0);
        BAR();                                 // all waves' frags consumed
        if (kt <= 5) SH(kt + 2);               // safe: overwrites kt's buffer
    }
#undef SH

    // ---- epilogue: G write (16 pairs x 2064B, f(e)=(e>>1)&3 swizzle) ----
#pragma unroll
    for (int am = 0; am < 4; am++) {
        const int cs = ((am & 1) << 1) + (h4 >> 1);
#pragma unroll
        for (int bn = 0; bn < 4; bn++) {
            const int p = (wr * 2 + (am >> 1)) * 4 + wc * 2 + (bn >> 1);
            const int e = ((bn & 1) << 4) + rl;
            unsigned int lo = (unsigned int)f2bf(acc[am][bn][0]) |
                              ((unsigned int)f2bf(acc[am][bn][1]) << 16);
            unsigned int hi = (unsigned int)f2bf(acc[am][bn][2]) |
                              ((unsigned int)f2bf(acc[am][bn][3]) << 16);
            u32x2 wv; wv[0] = lo; wv[1] = hi;
            *(u32x2*)(sm + p * 2064 + e * 64 +
                      ((cs ^ ((e >> 1) & 3)) << 4) + ((h4 & 1) << 3)) = wv;
        }
    }
    WLGKM0();                                  // G writes visible
    BAR();

    // ---- second GEMM: wave = K quarter kq; 16 pairs x 32 ch each ----
    const int kq = wid;
    f32x4 ae0 = (f32x4)0.f, ae1 = (f32x4)0.f;
    const char* grow = sm + rl * 2064;
#pragma unroll
    for (int es = 0; es < 8; es++) {
        const int e = kq * 8 + es;
        bf16x8 ga = *(const bf16x8*)(grow + e * 64 + ((h4 ^ ((e >> 1) & 3)) << 4));
        bf16x8 wb0 = *(const bf16x8*)(Wt3 + (size_t)e * 1024 + rl * 32 + h4 * 8);
        bf16x8 wb1 = *(const bf16x8*)(Wt3 + (size_t)e * 1024 + (16 + rl) * 32 + h4 * 8);
        ae0 = __builtin_amdgcn_mfma_f32_16x16x32_bf16(ga, wb0, ae0, 0, 0, 0);
        ae1 = __builtin_amdgcn_mfma_f32_16x16x32_bf16(ga, wb1, ae1, 0, 0, 0);
    }
    BAR();                                     // ga consumed -> G head reusable

    // ---- partials ps[kq][pair=h4*4+r][ch] (stride 34), overlays G[0,8704) ----
    float* ps = (float*)sm;
#pragma unroll
    for (int r = 0; r < 4; r++) {
        ps[(kq * 16 + h4 * 4 + r) * 34 + rl]      = ae0[r];
        ps[(kq * 16 + h4 * 4 + r) * 34 + 16 + rl] = ae1[r];
    }
    WLGKM0();                                  // ps writes visible
    BAR();

    // ---- reduce 4 K-quarters + bias + mask-norm + coalesced store ----
#pragma unroll
    for (int u = 0; u < 2; u++) {
        const int idx = u * 256 + t;
        const int p = idx >> 5, ch = idx & 31;
        float v = 0.f;
#pragma unroll
        for (int k2 = 0; k2 < 4; k2++)
            v += ps[(k2 * 16 + p) * 34 + ch];
        const int i = TI * 4 + (p >> 2), j = TJ * 4 + (p & 3);
        out[((size_t)(i * N_RES + j)) * CCH + ch] =
            (v + bout[ch]) * inv_norm[(size_t)i * N_RES + j];
    }
}

// ---------------------------------------------------------------------------
extern "C" void kernel_launch(void* const* d_in, const int* in_sizes, int n_in,
                              void* d_out, int out_size, void* d_ws, size_t ws_size,
                              hipStream_t stream)
{
    const float* m    = (const float*)d_in[0];
    const float* mask = (const float*)d_in[1];
    const float* gam  = (const float*)d_in[2];
    const float* bet  = (const float*)d_in[3];
    const float* Wa   = (const float*)d_in[4];
    const float* ba   = (const float*)d_in[5];
    const float* Wb   = (const float*)d_in[6];
    const float* bb   = (const float*)d_in[7];
    const float* Wout = (const float*)d_in[8];
    const float* bout = (const float*)d_in[9];
    float* out = (float*)d_out;

    char* ws = (char*)d_ws;
    char* Ag = ws;                                            //  8,388,608 B
    char* Bg = ws + 8388608;                                  //  8,388,608 B
    unsigned short* Wt3 = (unsigned short*)(ws + 16777216);   //     65,536 B
    float* inv_norm = (float*)(ws + 16842752);                //  1,048,576 B

    prep_ab<<<dim3(N_RES), dim3(256), 0, stream>>>(m, mask, gam, bet, Wa, ba, Wb, bb, Ag, Bg);
    kwt<<<dim3(128), dim3(256), 0, stream>>>(Wout, Wt3);
    knorm<<<dim3(64), dim3(256), 0, stream>>>(mask, inv_norm);
    kmain9<<<dim3(16384), dim3(256), 0, stream>>>(Ag, Bg, Wt3, inv_norm, bout, out);
}